// Round 14
// baseline (1447.956 us; speedup 1.0000x reference)
//
#include <hip/hip_runtime.h>
#include <stdint.h>

#define TT  1024
#define BB  512
#define OBS 128
#define HH  64
#define AA  18
#define RT  (TT*BB)                         // 524288 rows
#define OFF_L ((size_t)BB*HH)
#define OFF_V (OFF_L + (size_t)TT*BB*AA)

#define GI_ELEMS ((size_t)RT*192)           // 100,663,296 floats
#define WS_NEED  ((GI_ELEMS + (size_t)RT*HH)*4)   // 512 MiB exactly

typedef __attribute__((ext_vector_type(8))) short bf16x8;   // 8 bf16 (4 VGPR)
typedef __attribute__((ext_vector_type(4))) float f32x4;
typedef __attribute__((ext_vector_type(4))) unsigned int u32x4;

__device__ __forceinline__ float fast_rcp(float x){ return __builtin_amdgcn_rcpf(x); }
__device__ __forceinline__ float sigm(float x){ return fast_rcp(1.f + __expf(-x)); }
__device__ __forceinline__ float tanh_(float x){ return 1.f - 2.f*fast_rcp(1.f + __expf(2.f*x)); }

__device__ __forceinline__ unsigned bf16_rne(float f){      // round-to-nearest-even
    unsigned u = __float_as_uint(f);
    return (u + 0x7FFFu + ((u>>16)&1u)) >> 16;
}
__device__ __forceinline__ unsigned pk_bf16(float lo, float hi){
    unsigned d;
    asm("v_cvt_pk_bf16_f32 %0, %1, %2" : "=v"(d) : "v"(lo), "v"(hi));
    return d;
}

// ---- mask-dtype detection: any uint32 word >1 => byte-packed bool ----
__global__ void detect_mask(const uint32_t* __restrict__ m, uint32_t* __restrict__ flag)
{
    const int n_words = (TT * BB) / 4;
    uint32_t acc = 0;
    for (int i = blockIdx.x * blockDim.x + threadIdx.x; i < n_words;
         i += gridDim.x * blockDim.x)
        acc |= (m[i] > 1u) ? 1u : 0u;
    if (acc) flag[0] = 1u;
}

// ======== pass 1: gi = relu(x@W1+b1)@Wi+bi  — MFMA, zero barriers ========
#define P1_BLOCKS 1024
#define ZSTR 70    // z LDS stride (floats)

__global__ __launch_bounds__(256, 2)
void stem_gi(const float* __restrict__ x,
             const float* __restrict__ W1, const float* __restrict__ b1,
             const float* __restrict__ Wi, const float* __restrict__ bi,
             float* __restrict__ gi)
{
    const int tid = threadIdx.x, w = tid >> 6, l = tid & 63;
    const int a = l & 15, q = l >> 4;

    __shared__ float z_s[4][16*ZSTR];      // wave-private z transpose buffer
    float* zw = &z_s[w][0];

    bf16x8 W1f[4][4];                       // [n-tile][k-frag]
    #pragma unroll
    for (int nt = 0; nt < 4; ++nt)
        #pragma unroll
        for (int kf = 0; kf < 4; ++kf) {
            u32x4 pk;
            #pragma unroll
            for (int j2 = 0; j2 < 4; ++j2) {
                const int k0 = kf*32 + q*8 + 2*j2;
                pk[j2] = bf16_rne(W1[(size_t)k0*HH + nt*16 + a])
                       | (bf16_rne(W1[(size_t)(k0+1)*HH + nt*16 + a]) << 16);
            }
            W1f[nt][kf] = __builtin_bit_cast(bf16x8, pk);
        }
    float b1v[4];
    #pragma unroll
    for (int nt = 0; nt < 4; ++nt) b1v[nt] = b1[nt*16 + a];

    bf16x8 Wif[12][2];                      // [tau][k-frag]
    #pragma unroll
    for (int tau = 0; tau < 12; ++tau)
        #pragma unroll
        for (int kf = 0; kf < 2; ++kf) {
            u32x4 pk;
            #pragma unroll
            for (int j2 = 0; j2 < 4; ++j2) {
                const int k0 = kf*32 + q*8 + 2*j2;
                pk[j2] = bf16_rne(Wi[(size_t)k0*192 + tau*16 + a])
                       | (bf16_rne(Wi[(size_t)(k0+1)*192 + tau*16 + a]) << 16);
            }
            Wif[tau][kf] = __builtin_bit_cast(bf16x8, pk);
        }
    float biv[12];
    #pragma unroll
    for (int tau = 0; tau < 12; ++tau) biv[tau] = bi[tau*16 + a];

    for (int it = 0; it < 8; ++it) {
        const size_t grp  = (size_t)blockIdx.x*32 + it*4 + w;
        const float* xr   = x + (grp*16 + a)*OBS;

        float4 xv[8];
        #pragma unroll
        for (int kf = 0; kf < 4; ++kf) {
            xv[2*kf]   = *(const float4*)(xr + kf*32 + q*8);
            xv[2*kf+1] = *(const float4*)(xr + kf*32 + q*8 + 4);
        }
        bf16x8 Af[4];
        #pragma unroll
        for (int kf = 0; kf < 4; ++kf) {
            u32x4 pk;
            pk[0] = pk_bf16(xv[2*kf].x,   xv[2*kf].y);
            pk[1] = pk_bf16(xv[2*kf].z,   xv[2*kf].w);
            pk[2] = pk_bf16(xv[2*kf+1].x, xv[2*kf+1].y);
            pk[3] = pk_bf16(xv[2*kf+1].z, xv[2*kf+1].w);
            Af[kf] = __builtin_bit_cast(bf16x8, pk);
        }

        #pragma unroll
        for (int nt = 0; nt < 4; ++nt) {
            f32x4 D = {b1v[nt], b1v[nt], b1v[nt], b1v[nt]};
            #pragma unroll
            for (int kf = 0; kf < 4; ++kf)
                D = __builtin_amdgcn_mfma_f32_16x16x32_bf16(Af[kf], W1f[nt][kf], D, 0,0,0);
            #pragma unroll
            for (int e = 0; e < 4; ++e)
                zw[(q*4 + e)*ZSTR + nt*16 + a] = fmaxf(D[e], 0.f);
        }
        bf16x8 Az[2];
        #pragma unroll
        for (int s = 0; s < 2; ++s) {
            u32x4 pk;
            #pragma unroll
            for (int j2 = 0; j2 < 4; ++j2) {
                const float2 f = *(const float2*)(zw + a*ZSTR + s*32 + q*8 + 2*j2);
                pk[j2] = pk_bf16(f.x, f.y);
            }
            Az[s] = __builtin_bit_cast(bf16x8, pk);
        }

        float* gb = gi + grp*12*256 + l*4;
        #pragma unroll
        for (int tau = 0; tau < 12; ++tau) {
            f32x4 D = {biv[tau], biv[tau], biv[tau], biv[tau]};
            D = __builtin_amdgcn_mfma_f32_16x16x32_bf16(Az[0], Wif[tau][0], D, 0,0,0);
            D = __builtin_amdgcn_mfma_f32_16x16x32_bf16(Az[1], Wif[tau][1], D, 0,0,0);
            *(f32x4*)(gb + (size_t)tau*256) = D;
        }
    }
}

// ===== pass 2: serial GRU — TWO interleaved 16-chain groups per block =====
// Round-10 recur5 structure (proven 707us) with 2 independent groups per
// step: group B's MFMAs/loads fill group A's LDS/MFMA latency; ONE barrier
// (and one vmcnt drain) covers both. Keep the step body otherwise minimal.
__global__ __launch_bounds__(256)
void recur8(const float* __restrict__ gip,
            const void* __restrict__ mask_raw,
            const uint32_t* __restrict__ mflag,
            const float* __restrict__ ic,
            const float* __restrict__ Wh,
            const float* __restrict__ bhn,
            float* __restrict__ ys,
            float* __restrict__ out)
{
    const int blk = blockIdx.x;         // 0..15, 32 chains each
    const int tid = threadIdx.x;
    const int w   = tid >> 6;
    const int l   = tid & 63;
    const int a   = l & 15;             // A-row chain / within-tile col
    const int q   = l >> 4;
    const int dw  = w*16 + a;           // gate-dim this lane handles in D

    __shared__ float    h_lds[2][2][64][17];  // [grp][parity][dim][chain]
    __shared__ uint32_t mbits[2][TT];         // bit c = mask[t][base+G*16+c]

    // ---- stage mask bits via ballot, both groups
    if (mflag[0] != 0) {
        const uint8_t* m8 = (const uint8_t*)mask_raw;
        #pragma unroll
        for (int G = 0; G < 2; ++G)
            for (int t0 = w*4; t0 < TT; t0 += 16) {
                const int tt = t0 + q;
                const uint64_t bal =
                    __ballot(m8[(size_t)tt*BB + blk*32 + G*16 + a] != 0);
                if (l < 4) mbits[G][t0 + l] = (uint32_t)((bal >> (16*l)) & 0xFFFFu);
            }
    } else {
        const int32_t* m32 = (const int32_t*)mask_raw;
        #pragma unroll
        for (int G = 0; G < 2; ++G)
            for (int t0 = w*4; t0 < TT; t0 += 16) {
                const int tt = t0 + q;
                const uint64_t bal =
                    __ballot(m32[(size_t)tt*BB + blk*32 + G*16 + a] != 0);
                if (l < 4) mbits[G][t0 + l] = (uint32_t)((bal >> (16*l)) & 0xFFFFu);
            }
    }
    // ---- h(0-) = initial_carry, transposed [d][c], both groups
    for (int i = tid; i < 2*16*64; i += 256) {
        const int G = i >> 10, j = i & 1023;
        const int c = j & 15, d = j >> 4;
        h_lds[G][0][d][c] = ic[(blk*32 + G*16 + c)*HH + d];
    }

    // ---- Wh B-frags (shared across groups)
    bf16x8 Bf[3][2];
    #pragma unroll
    for (int g = 0; g < 3; ++g) {
        const int colb = g*64 + dw;
        #pragma unroll
        for (int s = 0; s < 2; ++s) {
            u32x4 pk;
            #pragma unroll
            for (int j2 = 0; j2 < 4; ++j2) {
                const int k0 = s*32 + q*8 + j2*2;
                pk[j2] = bf16_rne(Wh[(size_t)k0*192 + colb])
                       | (bf16_rne(Wh[(size_t)(k0+1)*192 + colb]) << 16);
            }
            Bf[g][s] = __builtin_bit_cast(bf16x8, pk);
        }
    }
    // ---- per-group ic A-frags + combine-side state
    u32x4 icA[2][2];
    #pragma unroll
    for (int G = 0; G < 2; ++G)
        #pragma unroll
        for (int s = 0; s < 2; ++s)
            #pragma unroll
            for (int j2 = 0; j2 < 4; ++j2) {
                const int d0 = s*32 + q*8 + j2*2;
                icA[G][s][j2] = bf16_rne(ic[(blk*32 + G*16 + a)*HH + d0])
                              | (bf16_rne(ic[(blk*32 + G*16 + a)*HH + d0 + 1]) << 16);
            }
    float ic_c[2][4], h_reg[2][4];
    #pragma unroll
    for (int G = 0; G < 2; ++G)
        #pragma unroll
        for (int e = 0; e < 4; ++e) {
            ic_c[G][e]  = ic[(blk*32 + G*16 + q*4 + e)*HH + dw];
            h_reg[G][e] = ic_c[G][e];
        }
    const float bhnv = bhn[dw];
    const f32x4 Cn = {bhnv, bhnv, bhnv, bhnv};

    __syncthreads();

    // gi (permuted): grp index per t spans 32 groups; this block owns 2b,2b+1
    #define GSTRIDE ((size_t)32*12*256)
    const float* gbase0 = gip + (size_t)(blk*2 + 0)*12*256 + l*4;
    const float* gbase1 = gip + (size_t)(blk*2 + 1)*12*256 + l*4;
    f32x4 bufA[2][3], bufB[2][3];
    #pragma unroll
    for (int g = 0; g < 3; ++g) {
        bufA[0][g] = *(const f32x4*)(gbase0 + 0*GSTRIDE + (size_t)(g*4 + w)*256);
        bufA[1][g] = *(const f32x4*)(gbase1 + 0*GSTRIDE + (size_t)(g*4 + w)*256);
        bufB[0][g] = *(const f32x4*)(gbase0 + 1*GSTRIDE + (size_t)(g*4 + w)*256);
        bufB[1][g] = *(const f32x4*)(gbase1 + 1*GSTRIDE + (size_t)(g*4 + w)*256);
    }

    auto step = [&](int t, f32x4 (&cur)[2][3]) {
        const int p = t & 1;
        const int tp = (t + 2 < TT) ? (t + 2) : (TT - 1);
        // ---- A-frags for both groups (LDS reads issue together)
        bf16x8 A0[2], A1[2];
        uint32_t mbv[2];
        #pragma unroll
        for (int G = 0; G < 2; ++G) {
            const uint32_t mb = mbits[G][t];
            mbv[G] = mb;
            const bool mA = (mb >> a) & 1;
            u32x4 Apk0, Apk1;
            #pragma unroll
            for (int j2 = 0; j2 < 4; ++j2) {
                const int d0 = q*8 + j2*2;
                const unsigned r0 = pk_bf16(h_lds[G][p][d0][a],    h_lds[G][p][d0+1][a]);
                const unsigned r1 = pk_bf16(h_lds[G][p][32+d0][a], h_lds[G][p][32+d0+1][a]);
                Apk0[j2] = mA ? icA[G][0][j2] : r0;
                Apk1[j2] = mA ? icA[G][1][j2] : r1;
            }
            A0[G] = __builtin_bit_cast(bf16x8, Apk0);
            A1[G] = __builtin_bit_cast(bf16x8, Apk1);
        }
        // ---- 12 MFMAs (two independent chains interleave in the pipe)
        f32x4 Dr[2], Dz[2], Dn[2], gin[2];
        #pragma unroll
        for (int G = 0; G < 2; ++G) {
            Dr[G] = __builtin_amdgcn_mfma_f32_16x16x32_bf16(A0[G], Bf[0][0], cur[G][0], 0,0,0);
            Dr[G] = __builtin_amdgcn_mfma_f32_16x16x32_bf16(A1[G], Bf[0][1], Dr[G],     0,0,0);
            Dz[G] = __builtin_amdgcn_mfma_f32_16x16x32_bf16(A0[G], Bf[1][0], cur[G][1], 0,0,0);
            Dz[G] = __builtin_amdgcn_mfma_f32_16x16x32_bf16(A1[G], Bf[1][1], Dz[G],     0,0,0);
            Dn[G] = __builtin_amdgcn_mfma_f32_16x16x32_bf16(A0[G], Bf[2][0], Cn,        0,0,0);
            Dn[G] = __builtin_amdgcn_mfma_f32_16x16x32_bf16(A1[G], Bf[2][1], Dn[G],     0,0,0);
            gin[G] = cur[G][2];
        }
        // ---- refill both groups for t+2
        #pragma unroll
        for (int g = 0; g < 3; ++g) {
            cur[0][g] = *(const f32x4*)(gbase0 + (size_t)tp*GSTRIDE + (size_t)(g*4 + w)*256);
            cur[1][g] = *(const f32x4*)(gbase1 + (size_t)tp*GSTRIDE + (size_t)(g*4 + w)*256);
        }
        // ---- elementwise + publish, both groups
        #pragma unroll
        for (int G = 0; G < 2; ++G) {
            float* ysp = ys + ((size_t)t*BB + blk*32 + G*16 + q*4)*HH + dw;
            #pragma unroll
            for (int e = 0; e < 4; ++e) {
                const bool me   = (mbv[G] >> (q*4 + e)) & 1;
                const float he  = me ? ic_c[G][e] : h_reg[G][e];
                const float r   = sigm(Dr[G][e]);
                const float u   = sigm(Dz[G][e]);
                const float n   = tanh_(fmaf(r, Dn[G][e], gin[G][e]));
                const float hn  = fmaf(u, he - n, n);
                h_reg[G][e] = hn;
                h_lds[G][p ^ 1][dw][q*4 + e] = hn;
                ysp[(size_t)e*HH] = hn;
            }
        }
        __syncthreads();   // h(t) published for all waves' A-frags
    };

    for (int t = 0; t < TT; t += 2) {
        step(t,     bufA);
        step(t + 1, bufB);
    }
    #pragma unroll
    for (int G = 0; G < 2; ++G)
        #pragma unroll
        for (int e = 0; e < 4; ++e)
            out[(size_t)(blk*32 + G*16 + q*4 + e)*HH + dw] = h_reg[G][e];
    #undef GSTRIDE
}

// ================= pass 3: heads, wave-local, no barriers ===============
#define P3_BLOCKS 1024
#define P3_RPW (RT/(P3_BLOCKS*4))   // 128 rows per wave

__global__ __launch_bounds__(256, 2)
void heads(const float* __restrict__ ys,
           const float* __restrict__ W2, const float* __restrict__ b2,
           const float* __restrict__ Wl, const float* __restrict__ bl,
           const float* __restrict__ Wv, const float* __restrict__ bv,
           float* __restrict__ out)
{
    const int tid = threadIdx.x, w = tid >> 6, lane = tid & 63;
    __shared__ float4 sb[4][2][16];
    float w2r[64];
    #pragma unroll
    for (int k = 0; k < 64; ++k) w2r[k] = W2[k*HH + lane];
    const float b2v = b2[lane];
    float wc[64]; float bcv = 0.f;
    if (lane < AA) {
        #pragma unroll
        for (int k = 0; k < 64; ++k) wc[k] = Wl[k*AA + lane];
        bcv = bl[lane];
    } else if (lane == AA) {
        #pragma unroll
        for (int k = 0; k < 64; ++k) wc[k] = Wv[k];
        bcv = bv[0];
    } else {
        #pragma unroll
        for (int k = 0; k < 64; ++k) wc[k] = 0.f;
    }
    const int r0 = (blockIdx.x*4 + w) * P3_RPW;
    float ysA = ys[(size_t)r0*HH + lane];
    float ysB = ys[(size_t)(r0+1)*HH + lane];
    for (int rr = 0; rr < P3_RPW; ++rr) {
        const int row = r0 + rr;
        const float ysv = ysA;
        ysA = ysB;
        const int rn = (rr+2 < P3_RPW) ? (row+2) : (r0 + P3_RPW - 1);
        ysB = ys[(size_t)rn*HH + lane];
        ((float*)&sb[w][0][0])[lane] = ysv;
        float acc = b2v;
        {
            const float4* yb = &sb[w][0][0];
            #pragma unroll
            for (int kk = 0; kk < 16; ++kk) {
                const float4 v = yb[kk];
                acc += w2r[4*kk+0]*v.x + w2r[4*kk+1]*v.y
                     + w2r[4*kk+2]*v.z + w2r[4*kk+3]*v.w;
            }
        }
        const float yv = fmaxf(acc, 0.f);
        ((float*)&sb[w][1][0])[lane] = yv;
        float acc2 = bcv;
        {
            const float4* yb = &sb[w][1][0];
            #pragma unroll
            for (int kk = 0; kk < 16; ++kk) {
                const float4 v = yb[kk];
                acc2 += wc[4*kk+0]*v.x + wc[4*kk+1]*v.y
                      + wc[4*kk+2]*v.z + wc[4*kk+3]*v.w;
            }
        }
        if (lane < AA)       out[OFF_L + (size_t)row*AA + lane] = acc2;
        else if (lane == AA) out[OFF_V + row] = acc2;
    }
}

// ================= fallback: round-2 fused kernel (known-correct) =======
__global__ __launch_bounds__(256, 2)
void gru_agent(const float* __restrict__ x,
               const void* __restrict__ mask_raw,
               const uint32_t* __restrict__ mask_flag,
               const float* __restrict__ ic,
               const float* __restrict__ W1, const float* __restrict__ b1,
               const float* __restrict__ Wi, const float* __restrict__ bi,
               const float* __restrict__ Wh, const float* __restrict__ bhn,
               const float* __restrict__ W2, const float* __restrict__ b2,
               const float* __restrict__ Wl, const float* __restrict__ bl,
               const float* __restrict__ Wv, const float* __restrict__ bv,
               float* __restrict__ out)
{
    const int b    = blockIdx.x;
    const int tid  = threadIdx.x;
    const int w    = tid >> 6;
    const int lane = tid & 63;

    const bool mask_is_u8 = (mask_flag[0] != 0);
    const uint8_t* __restrict__ m8  = (const uint8_t*)mask_raw;
    const int32_t* __restrict__ m32 = (const int32_t*)mask_raw;

    __shared__ float4 x_l[2][4][9];
    __shared__ float4 z_l[16];
    __shared__ float4 h_l[2][16];
    __shared__ float4 y_l[2][16];
    __shared__ float4 ic_l[16];
    __shared__ float  gi_l[192];
    __shared__ float  gh_l[192];

    const int js = (w << 4) | (lane >> 2);
    const int kc = lane & 3;
    float w1r[32];
    #pragma unroll
    for (int i = 0; i < 32; ++i) w1r[i] = W1[(kc*32 + i)*HH + js];
    const float b1v = b1[js];

    float wA[64], wB[64];
    float biv = 0.f, b2v = 0.f, blv = 0.f;
    if (w < 3) {
        const int n = tid;
        #pragma unroll
        for (int k = 0; k < 64; ++k) wA[k] = Wi[k*(3*HH) + n];
        #pragma unroll
        for (int k = 0; k < 64; ++k) wB[k] = Wh[k*(3*HH) + n];
        biv = bi[n];
    } else {
        #pragma unroll
        for (int k = 0; k < 64; ++k) wA[k] = W2[k*HH + lane];
        #pragma unroll
        for (int k = 0; k < 64; ++k) wB[k] = (lane < AA) ? Wl[k*AA + lane]
                                           : (lane == AA ? Wv[k] : 0.f);
        b2v = b2[lane];
        blv = (lane < AA) ? bl[lane] : (lane == AA ? bv[0] : 0.f);
    }
    const float bhnv = (tid < HH) ? bhn[tid] : 0.f;

    if (tid < HH) {
        float v = ic[b*HH + tid];
        ((float*)ic_l)[tid]   = v;
        ((float*)h_l[0])[tid] = v;
    }
    if (tid < OBS) {
        float xv = x[(0*BB + b)*OBS + tid];
        ((float*)&x_l[0][tid>>5])[tid&31] = xv;
    }
    uint8_t m_cur = mask_is_u8 ? m8[b] : (uint8_t)(m32[b] != 0);
    __syncthreads();

    for (int t = 0; t < TT + 2; ++t) {
        const int p = t & 1;
        float xnext = 0.f;
        if (t + 1 < TT && tid < OBS) xnext = x[((t+1)*BB + b)*OBS + tid];
        uint8_t m_next = 0;
        if (t + 1 < TT) {
            const int mi = (t+1)*BB + b;
            m_next = mask_is_u8 ? m8[mi] : (uint8_t)(m32[mi] != 0);
        }
        if (t < TT) {
            const float4* xr = &x_l[p][kc][0];
            float acc = 0.f;
            #pragma unroll
            for (int qq = 0; qq < 8; ++qq) {
                float4 xv = xr[qq];
                acc += w1r[4*qq+0]*xv.x + w1r[4*qq+1]*xv.y
                     + w1r[4*qq+2]*xv.z + w1r[4*qq+3]*xv.w;
            }
            acc += __shfl_xor(acc, 1);
            acc += __shfl_xor(acc, 2);
            if (kc == 0) ((float*)z_l)[js] = fmaxf(acc + b1v, 0.f);
        }
        if (t < TT && w < 3) {
            const float4* hs = m_cur ? ic_l : h_l[p];
            float acc = 0.f;
            #pragma unroll
            for (int kk = 0; kk < 16; ++kk) {
                float4 hv = hs[kk];
                acc += wB[4*kk+0]*hv.x + wB[4*kk+1]*hv.y
                     + wB[4*kk+2]*hv.z + wB[4*kk+3]*hv.w;
            }
            gh_l[tid] = acc;
        } else if (w == 3 && t >= 1 && t <= TT) {
            const float4* hs = h_l[p];
            float acc = b2v;
            #pragma unroll
            for (int kk = 0; kk < 16; ++kk) {
                float4 hv = hs[kk];
                acc += wA[4*kk+0]*hv.x + wA[4*kk+1]*hv.y
                     + wA[4*kk+2]*hv.z + wA[4*kk+3]*hv.w;
            }
            ((float*)y_l[p])[lane] = fmaxf(acc, 0.f);
        }
        __syncthreads();
        if (t < TT && w < 3) {
            float acc = biv;
            #pragma unroll
            for (int kk = 0; kk < 16; ++kk) {
                float4 zv = z_l[kk];
                acc += wA[4*kk+0]*zv.x + wA[4*kk+1]*zv.y
                     + wA[4*kk+2]*zv.z + wA[4*kk+3]*zv.w;
            }
            gi_l[tid] = acc;
        } else if (w == 3 && t >= 2) {
            const float4* yss = y_l[p ^ 1];
            float acc = blv;
            #pragma unroll
            for (int kk = 0; kk < 16; ++kk) {
                float4 yv = yss[kk];
                acc += wB[4*kk+0]*yv.x + wB[4*kk+1]*yv.y
                     + wB[4*kk+2]*yv.z + wB[4*kk+3]*yv.w;
            }
            if (lane < AA)       out[OFF_L + (size_t)((t-2)*BB + b)*AA + lane] = acc;
            else if (lane == AA) out[OFF_V + (size_t)(t-2)*BB + b] = acc;
        }
        __syncthreads();
        if (t < TT && tid < HH) {
            const int j = tid;
            const float irv = gi_l[j], izv = gi_l[HH+j], inn = gi_l[2*HH+j];
            const float hrv = gh_l[j], hzv = gh_l[HH+j], hnv = gh_l[2*HH+j];
            const float heff = m_cur ? ((const float*)ic_l)[j]
                                     : ((const float*)h_l[p])[j];
            const float r  = sigm(irv + hrv);
            const float u  = sigm(izv + hzv);
            const float nn = tanh_(inn + r*(hnv + bhnv));
            ((float*)h_l[p ^ 1])[j] = u*(heff - nn) + nn;
        }
        if (t + 1 < TT && tid < OBS) {
            ((float*)&x_l[p ^ 1][tid>>5])[tid&31] = xnext;
        }
        m_cur = m_next;
        __syncthreads();
    }
    if (tid < HH) out[(size_t)b*HH + tid] = ((const float*)h_l[TT & 1])[tid];
}

extern "C" void kernel_launch(void* const* d_in, const int* in_sizes, int n_in,
                              void* d_out, int out_size, void* d_ws, size_t ws_size,
                              hipStream_t stream) {
    const float* x    = (const float*)d_in[0];
    const void*  mask = (const void*) d_in[1];
    const float* ic   = (const float*)d_in[2];
    const float* W1   = (const float*)d_in[3];
    const float* b1   = (const float*)d_in[4];
    const float* Wi   = (const float*)d_in[5];
    const float* bi   = (const float*)d_in[6];
    const float* Wh   = (const float*)d_in[7];
    const float* bhn  = (const float*)d_in[8];
    const float* W2   = (const float*)d_in[9];
    const float* b2   = (const float*)d_in[10];
    const float* Wl   = (const float*)d_in[11];
    const float* bl   = (const float*)d_in[12];
    const float* Wv   = (const float*)d_in[13];
    const float* bv   = (const float*)d_in[14];
    float* out = (float*)d_out;

    if (ws_size >= WS_NEED) {
        float* gi = (float*)d_ws;
        float* ys = gi + GI_ELEMS;
        // flag lives in out[last value elem]; heads overwrites it last
        uint32_t* flag = (uint32_t*)(out + OFF_V + RT - 1);
        hipMemsetAsync(flag, 0, sizeof(uint32_t), stream);
        detect_mask<<<64, 256, 0, stream>>>((const uint32_t*)mask, flag);
        stem_gi<<<P1_BLOCKS, 256, 0, stream>>>(x, W1, b1, Wi, bi, gi);
        recur8<<<16, 256, 0, stream>>>(gi, mask, flag, ic, Wh, bhn, ys, out);
        heads<<<P3_BLOCKS, 256, 0, stream>>>(ys, W2, b2, Wl, bl, Wv, bv, out);
    } else {
        uint32_t* flag = (uint32_t*)d_ws;
        hipMemsetAsync(flag, 0, sizeof(uint32_t), stream);
        detect_mask<<<64, 256, 0, stream>>>((const uint32_t*)mask, flag);
        gru_agent<<<BB, 256, 0, stream>>>(x, mask, flag, ic, W1, b1, Wi, bi, Wh, bhn,
                                          W2, b2, Wl, bl, Wv, bv, out);
    }
}

// Round 15
// 1004.179 us; speedup vs baseline: 1.4419x; 1.4419x over previous
//
#include <hip/hip_runtime.h>
#include <stdint.h>

#define TT  1024
#define BB  512
#define OBS 128
#define HH  64
#define AA  18
#define RT  (TT*BB)                         // 524288 rows
#define OFF_L ((size_t)BB*HH)
#define OFF_V (OFF_L + (size_t)TT*BB*AA)

#define GI_ELEMS ((size_t)RT*192)           // 100,663,296 floats
#define WS_NEED  ((GI_ELEMS + (size_t)RT*HH)*4)   // 512 MiB exactly

typedef __attribute__((ext_vector_type(8))) short bf16x8;   // 8 bf16 (4 VGPR)
typedef __attribute__((ext_vector_type(4))) float f32x4;
typedef __attribute__((ext_vector_type(4))) unsigned int u32x4;

__device__ __forceinline__ float fast_rcp(float x){ return __builtin_amdgcn_rcpf(x); }
__device__ __forceinline__ float sigm(float x){ return fast_rcp(1.f + __expf(-x)); }
__device__ __forceinline__ float tanh_(float x){ return 1.f - 2.f*fast_rcp(1.f + __expf(2.f*x)); }

__device__ __forceinline__ unsigned bf16_rne(float f){      // round-to-nearest-even
    unsigned u = __float_as_uint(f);
    return (u + 0x7FFFu + ((u>>16)&1u)) >> 16;
}
__device__ __forceinline__ unsigned pk_bf16(float lo, float hi){
    unsigned d;
    asm("v_cvt_pk_bf16_f32 %0, %1, %2" : "=v"(d) : "v"(lo), "v"(hi));
    return d;
}

// ---- mask-dtype detection: any uint32 word >1 => byte-packed bool ----
__global__ void detect_mask(const uint32_t* __restrict__ m, uint32_t* __restrict__ flag)
{
    const int n_words = (TT * BB) / 4;
    uint32_t acc = 0;
    for (int i = blockIdx.x * blockDim.x + threadIdx.x; i < n_words;
         i += gridDim.x * blockDim.x)
        acc |= (m[i] > 1u) ? 1u : 0u;
    if (acc) flag[0] = 1u;
}

// ======== pass 1: gi = relu(x@W1+b1)@Wi+bi  — MFMA, zero barriers ========
#define P1_BLOCKS 1024
#define ZSTR 70    // z LDS stride (floats)

__global__ __launch_bounds__(256, 2)
void stem_gi(const float* __restrict__ x,
             const float* __restrict__ W1, const float* __restrict__ b1,
             const float* __restrict__ Wi, const float* __restrict__ bi,
             float* __restrict__ gi)
{
    const int tid = threadIdx.x, w = tid >> 6, l = tid & 63;
    const int a = l & 15, q = l >> 4;

    __shared__ float z_s[4][16*ZSTR];      // wave-private z transpose buffer
    float* zw = &z_s[w][0];

    bf16x8 W1f[4][4];                       // [n-tile][k-frag]
    #pragma unroll
    for (int nt = 0; nt < 4; ++nt)
        #pragma unroll
        for (int kf = 0; kf < 4; ++kf) {
            u32x4 pk;
            #pragma unroll
            for (int j2 = 0; j2 < 4; ++j2) {
                const int k0 = kf*32 + q*8 + 2*j2;
                pk[j2] = bf16_rne(W1[(size_t)k0*HH + nt*16 + a])
                       | (bf16_rne(W1[(size_t)(k0+1)*HH + nt*16 + a]) << 16);
            }
            W1f[nt][kf] = __builtin_bit_cast(bf16x8, pk);
        }
    float b1v[4];
    #pragma unroll
    for (int nt = 0; nt < 4; ++nt) b1v[nt] = b1[nt*16 + a];

    bf16x8 Wif[12][2];                      // [tau][k-frag]
    #pragma unroll
    for (int tau = 0; tau < 12; ++tau)
        #pragma unroll
        for (int kf = 0; kf < 2; ++kf) {
            u32x4 pk;
            #pragma unroll
            for (int j2 = 0; j2 < 4; ++j2) {
                const int k0 = kf*32 + q*8 + 2*j2;
                pk[j2] = bf16_rne(Wi[(size_t)k0*192 + tau*16 + a])
                       | (bf16_rne(Wi[(size_t)(k0+1)*192 + tau*16 + a]) << 16);
            }
            Wif[tau][kf] = __builtin_bit_cast(bf16x8, pk);
        }
    float biv[12];
    #pragma unroll
    for (int tau = 0; tau < 12; ++tau) biv[tau] = bi[tau*16 + a];

    for (int it = 0; it < 8; ++it) {
        const size_t grp  = (size_t)blockIdx.x*32 + it*4 + w;
        const float* xr   = x + (grp*16 + a)*OBS;

        float4 xv[8];
        #pragma unroll
        for (int kf = 0; kf < 4; ++kf) {
            xv[2*kf]   = *(const float4*)(xr + kf*32 + q*8);
            xv[2*kf+1] = *(const float4*)(xr + kf*32 + q*8 + 4);
        }
        bf16x8 Af[4];
        #pragma unroll
        for (int kf = 0; kf < 4; ++kf) {
            u32x4 pk;
            pk[0] = pk_bf16(xv[2*kf].x,   xv[2*kf].y);
            pk[1] = pk_bf16(xv[2*kf].z,   xv[2*kf].w);
            pk[2] = pk_bf16(xv[2*kf+1].x, xv[2*kf+1].y);
            pk[3] = pk_bf16(xv[2*kf+1].z, xv[2*kf+1].w);
            Af[kf] = __builtin_bit_cast(bf16x8, pk);
        }

        #pragma unroll
        for (int nt = 0; nt < 4; ++nt) {
            f32x4 D = {b1v[nt], b1v[nt], b1v[nt], b1v[nt]};
            #pragma unroll
            for (int kf = 0; kf < 4; ++kf)
                D = __builtin_amdgcn_mfma_f32_16x16x32_bf16(Af[kf], W1f[nt][kf], D, 0,0,0);
            #pragma unroll
            for (int e = 0; e < 4; ++e)
                zw[(q*4 + e)*ZSTR + nt*16 + a] = fmaxf(D[e], 0.f);
        }
        bf16x8 Az[2];
        #pragma unroll
        for (int s = 0; s < 2; ++s) {
            u32x4 pk;
            #pragma unroll
            for (int j2 = 0; j2 < 4; ++j2) {
                const float2 f = *(const float2*)(zw + a*ZSTR + s*32 + q*8 + 2*j2);
                pk[j2] = pk_bf16(f.x, f.y);
            }
            Az[s] = __builtin_bit_cast(bf16x8, pk);
        }

        float* gb = gi + grp*12*256 + l*4;
        #pragma unroll
        for (int tau = 0; tau < 12; ++tau) {
            f32x4 D = {biv[tau], biv[tau], biv[tau], biv[tau]};
            D = __builtin_amdgcn_mfma_f32_16x16x32_bf16(Az[0], Wif[tau][0], D, 0,0,0);
            D = __builtin_amdgcn_mfma_f32_16x16x32_bf16(Az[1], Wif[tau][1], D, 0,0,0);
            *(f32x4*)(gb + (size_t)tau*256) = D;
        }
    }
}

// ===== pass 2: serial GRU — round-10 recur5 + raw barrier + depth-4 ======
// ONLY two changes vs the proven 707us kernel:
//  (1) __syncthreads -> lgkmcnt(0)+s_barrier  (gi loads stay in flight)
//  (2) prefetch depth 2 -> 4 (4 static buffers, 4x unrolled loop)
__global__ __launch_bounds__(256)
void recur9(const float* __restrict__ gip,
            const void* __restrict__ mask_raw,
            const uint32_t* __restrict__ mflag,
            const float* __restrict__ ic,
            const float* __restrict__ Wh,
            const float* __restrict__ bhn,
            float* __restrict__ ys,
            float* __restrict__ out)
{
    const int blk = blockIdx.x;         // 0..31, 16 chains each
    const int tid = threadIdx.x;
    const int w   = tid >> 6;
    const int l   = tid & 63;
    const int a   = l & 15;             // A-row chain / within-tile col
    const int q   = l >> 4;
    const int dw  = w*16 + a;           // gate-dim this lane handles in D

    __shared__ float    h_lds[2][64][17];   // [parity][dim][chain], padded
    __shared__ uint32_t mbits[TT];          // bit c = mask[t][blk*16+c]

    if (mflag[0] != 0) {
        const uint8_t* m8 = (const uint8_t*)mask_raw;
        for (int t0 = w*4; t0 < TT; t0 += 16) {
            const int tt = t0 + q;
            const uint64_t bal = __ballot(m8[(size_t)tt*BB + blk*16 + a] != 0);
            if (l < 4) mbits[t0 + l] = (uint32_t)((bal >> (16*l)) & 0xFFFFu);
        }
    } else {
        const int32_t* m32 = (const int32_t*)mask_raw;
        for (int t0 = w*4; t0 < TT; t0 += 16) {
            const int tt = t0 + q;
            const uint64_t bal = __ballot(m32[(size_t)tt*BB + blk*16 + a] != 0);
            if (l < 4) mbits[t0 + l] = (uint32_t)((bal >> (16*l)) & 0xFFFFu);
        }
    }
    for (int i = tid; i < 16*64; i += 256) {
        const int c = i & 15, d = i >> 4;
        h_lds[0][d][c] = ic[(blk*16 + c)*HH + d];
    }

    bf16x8 Bf[3][2];
    #pragma unroll
    for (int g = 0; g < 3; ++g) {
        const int colb = g*64 + dw;
        #pragma unroll
        for (int s = 0; s < 2; ++s) {
            u32x4 pk;
            #pragma unroll
            for (int j2 = 0; j2 < 4; ++j2) {
                const int k0 = s*32 + q*8 + j2*2;
                pk[j2] = bf16_rne(Wh[(size_t)k0*192 + colb])
                       | (bf16_rne(Wh[(size_t)(k0+1)*192 + colb]) << 16);
            }
            Bf[g][s] = __builtin_bit_cast(bf16x8, pk);
        }
    }
    u32x4 icA[2];
    #pragma unroll
    for (int s = 0; s < 2; ++s) {
        #pragma unroll
        for (int j2 = 0; j2 < 4; ++j2) {
            const int d0 = s*32 + q*8 + j2*2;
            icA[s][j2] = bf16_rne(ic[(blk*16 + a)*HH + d0])
                       | (bf16_rne(ic[(blk*16 + a)*HH + d0 + 1]) << 16);
        }
    }
    float ic_c[4], h_reg[4];
    #pragma unroll
    for (int e = 0; e < 4; ++e) {
        ic_c[e]  = ic[(blk*16 + q*4 + e)*HH + dw];
        h_reg[e] = ic_c[e];
    }
    const float bhnv = bhn[dw];
    const f32x4 Cn = {bhnv, bhnv, bhnv, bhnv};

    __syncthreads();   // staging done (full barrier once)

    #define GSTRIDE ((size_t)32*12*256)
    const float* gbase = gip + (size_t)blk*12*256 + l*4;
    f32x4 buf0[3], buf1[3], buf2[3], buf3[3];   // depth-4, static names
    #pragma unroll
    for (int g = 0; g < 3; ++g) {
        buf0[g] = *(const f32x4*)(gbase + 0*GSTRIDE + (size_t)(g*4 + w)*256);
        buf1[g] = *(const f32x4*)(gbase + 1*GSTRIDE + (size_t)(g*4 + w)*256);
        buf2[g] = *(const f32x4*)(gbase + 2*GSTRIDE + (size_t)(g*4 + w)*256);
        buf3[g] = *(const f32x4*)(gbase + 3*GSTRIDE + (size_t)(g*4 + w)*256);
    }

    auto step = [&](int t, f32x4* cur) {
        const int p = t & 1;
        const uint32_t mb = mbits[t];
        const bool mA = (mb >> a) & 1;
        u32x4 Apk0, Apk1;
        #pragma unroll
        for (int j2 = 0; j2 < 4; ++j2) {
            const int d0 = q*8 + j2*2;
            const unsigned r0 = pk_bf16(h_lds[p][d0][a],    h_lds[p][d0+1][a]);
            const unsigned r1 = pk_bf16(h_lds[p][32+d0][a], h_lds[p][32+d0+1][a]);
            Apk0[j2] = mA ? icA[0][j2] : r0;
            Apk1[j2] = mA ? icA[1][j2] : r1;
        }
        const bf16x8 A0 = __builtin_bit_cast(bf16x8, Apk0);
        const bf16x8 A1 = __builtin_bit_cast(bf16x8, Apk1);
        f32x4 Dr = __builtin_amdgcn_mfma_f32_16x16x32_bf16(A0, Bf[0][0], cur[0], 0,0,0);
        Dr       = __builtin_amdgcn_mfma_f32_16x16x32_bf16(A1, Bf[0][1], Dr,     0,0,0);
        f32x4 Dz = __builtin_amdgcn_mfma_f32_16x16x32_bf16(A0, Bf[1][0], cur[1], 0,0,0);
        Dz       = __builtin_amdgcn_mfma_f32_16x16x32_bf16(A1, Bf[1][1], Dz,     0,0,0);
        f32x4 Dn = __builtin_amdgcn_mfma_f32_16x16x32_bf16(A0, Bf[2][0], Cn,     0,0,0);
        Dn       = __builtin_amdgcn_mfma_f32_16x16x32_bf16(A1, Bf[2][1], Dn,     0,0,0);
        const f32x4 gin = cur[2];
        // refill this buffer for t+4 (stays in flight across raw barriers)
        const int tp = (t + 4 < TT) ? (t + 4) : (TT - 1);
        #pragma unroll
        for (int g = 0; g < 3; ++g)
            cur[g] = *(const f32x4*)(gbase + (size_t)tp*GSTRIDE + (size_t)(g*4 + w)*256);
        float* ysp = ys + ((size_t)t*BB + blk*16 + q*4)*HH + dw;
        #pragma unroll
        for (int e = 0; e < 4; ++e) {
            const bool me   = (mb >> (q*4 + e)) & 1;
            const float he  = me ? ic_c[e] : h_reg[e];
            const float r   = sigm(Dr[e]);
            const float u   = sigm(Dz[e]);
            const float n   = tanh_(fmaf(r, Dn[e], gin[e]));
            const float hn  = fmaf(u, he - n, n);
            h_reg[e] = hn;
            h_lds[p ^ 1][dw][q*4 + e] = hn;
            ysp[(size_t)e*HH] = hn;
        }
        // raw barrier: drain ONLY LDS (h writes); gi loads stay in flight
        asm volatile("s_waitcnt lgkmcnt(0)" ::: "memory");
        __builtin_amdgcn_s_barrier();
    };

    for (int t = 0; t < TT; t += 4) {
        step(t,     buf0);
        step(t + 1, buf1);
        step(t + 2, buf2);
        step(t + 3, buf3);
    }
    #pragma unroll
    for (int e = 0; e < 4; ++e)
        out[(size_t)(blk*16 + q*4 + e)*HH + dw] = h_reg[e];
    #undef GSTRIDE
}

// ================= pass 3: heads, wave-local, no barriers ===============
#define P3_BLOCKS 1024
#define P3_RPW (RT/(P3_BLOCKS*4))   // 128 rows per wave

__global__ __launch_bounds__(256, 2)
void heads(const float* __restrict__ ys,
           const float* __restrict__ W2, const float* __restrict__ b2,
           const float* __restrict__ Wl, const float* __restrict__ bl,
           const float* __restrict__ Wv, const float* __restrict__ bv,
           float* __restrict__ out)
{
    const int tid = threadIdx.x, w = tid >> 6, lane = tid & 63;
    __shared__ float4 sb[4][2][16];
    float w2r[64];
    #pragma unroll
    for (int k = 0; k < 64; ++k) w2r[k] = W2[k*HH + lane];
    const float b2v = b2[lane];
    float wc[64]; float bcv = 0.f;
    if (lane < AA) {
        #pragma unroll
        for (int k = 0; k < 64; ++k) wc[k] = Wl[k*AA + lane];
        bcv = bl[lane];
    } else if (lane == AA) {
        #pragma unroll
        for (int k = 0; k < 64; ++k) wc[k] = Wv[k];
        bcv = bv[0];
    } else {
        #pragma unroll
        for (int k = 0; k < 64; ++k) wc[k] = 0.f;
    }
    const int r0 = (blockIdx.x*4 + w) * P3_RPW;
    float ysA = ys[(size_t)r0*HH + lane];
    float ysB = ys[(size_t)(r0+1)*HH + lane];
    for (int rr = 0; rr < P3_RPW; ++rr) {
        const int row = r0 + rr;
        const float ysv = ysA;
        ysA = ysB;
        const int rn = (rr+2 < P3_RPW) ? (row+2) : (r0 + P3_RPW - 1);
        ysB = ys[(size_t)rn*HH + lane];
        ((float*)&sb[w][0][0])[lane] = ysv;
        float acc = b2v;
        {
            const float4* yb = &sb[w][0][0];
            #pragma unroll
            for (int kk = 0; kk < 16; ++kk) {
                const float4 v = yb[kk];
                acc += w2r[4*kk+0]*v.x + w2r[4*kk+1]*v.y
                     + w2r[4*kk+2]*v.z + w2r[4*kk+3]*v.w;
            }
        }
        const float yv = fmaxf(acc, 0.f);
        ((float*)&sb[w][1][0])[lane] = yv;
        float acc2 = bcv;
        {
            const float4* yb = &sb[w][1][0];
            #pragma unroll
            for (int kk = 0; kk < 16; ++kk) {
                const float4 v = yb[kk];
                acc2 += wc[4*kk+0]*v.x + wc[4*kk+1]*v.y
                      + wc[4*kk+2]*v.z + wc[4*kk+3]*v.w;
            }
        }
        if (lane < AA)       out[OFF_L + (size_t)row*AA + lane] = acc2;
        else if (lane == AA) out[OFF_V + row] = acc2;
    }
}

// ================= fallback: round-2 fused kernel (known-correct) =======
__global__ __launch_bounds__(256, 2)
void gru_agent(const float* __restrict__ x,
               const void* __restrict__ mask_raw,
               const uint32_t* __restrict__ mask_flag,
               const float* __restrict__ ic,
               const float* __restrict__ W1, const float* __restrict__ b1,
               const float* __restrict__ Wi, const float* __restrict__ bi,
               const float* __restrict__ Wh, const float* __restrict__ bhn,
               const float* __restrict__ W2, const float* __restrict__ b2,
               const float* __restrict__ Wl, const float* __restrict__ bl,
               const float* __restrict__ Wv, const float* __restrict__ bv,
               float* __restrict__ out)
{
    const int b    = blockIdx.x;
    const int tid  = threadIdx.x;
    const int w    = tid >> 6;
    const int lane = tid & 63;

    const bool mask_is_u8 = (mask_flag[0] != 0);
    const uint8_t* __restrict__ m8  = (const uint8_t*)mask_raw;
    const int32_t* __restrict__ m32 = (const int32_t*)mask_raw;

    __shared__ float4 x_l[2][4][9];
    __shared__ float4 z_l[16];
    __shared__ float4 h_l[2][16];
    __shared__ float4 y_l[2][16];
    __shared__ float4 ic_l[16];
    __shared__ float  gi_l[192];
    __shared__ float  gh_l[192];

    const int js = (w << 4) | (lane >> 2);
    const int kc = lane & 3;
    float w1r[32];
    #pragma unroll
    for (int i = 0; i < 32; ++i) w1r[i] = W1[(kc*32 + i)*HH + js];
    const float b1v = b1[js];

    float wA[64], wB[64];
    float biv = 0.f, b2v = 0.f, blv = 0.f;
    if (w < 3) {
        const int n = tid;
        #pragma unroll
        for (int k = 0; k < 64; ++k) wA[k] = Wi[k*(3*HH) + n];
        #pragma unroll
        for (int k = 0; k < 64; ++k) wB[k] = Wh[k*(3*HH) + n];
        biv = bi[n];
    } else {
        #pragma unroll
        for (int k = 0; k < 64; ++k) wA[k] = W2[k*HH + lane];
        #pragma unroll
        for (int k = 0; k < 64; ++k) wB[k] = (lane < AA) ? Wl[k*AA + lane]
                                           : (lane == AA ? Wv[k] : 0.f);
        b2v = b2[lane];
        blv = (lane < AA) ? bl[lane] : (lane == AA ? bv[0] : 0.f);
    }
    const float bhnv = (tid < HH) ? bhn[tid] : 0.f;

    if (tid < HH) {
        float v = ic[b*HH + tid];
        ((float*)ic_l)[tid]   = v;
        ((float*)h_l[0])[tid] = v;
    }
    if (tid < OBS) {
        float xv = x[(0*BB + b)*OBS + tid];
        ((float*)&x_l[0][tid>>5])[tid&31] = xv;
    }
    uint8_t m_cur = mask_is_u8 ? m8[b] : (uint8_t)(m32[b] != 0);
    __syncthreads();

    for (int t = 0; t < TT + 2; ++t) {
        const int p = t & 1;
        float xnext = 0.f;
        if (t + 1 < TT && tid < OBS) xnext = x[((t+1)*BB + b)*OBS + tid];
        uint8_t m_next = 0;
        if (t + 1 < TT) {
            const int mi = (t+1)*BB + b;
            m_next = mask_is_u8 ? m8[mi] : (uint8_t)(m32[mi] != 0);
        }
        if (t < TT) {
            const float4* xr = &x_l[p][kc][0];
            float acc = 0.f;
            #pragma unroll
            for (int qq = 0; qq < 8; ++qq) {
                float4 xv = xr[qq];
                acc += w1r[4*qq+0]*xv.x + w1r[4*qq+1]*xv.y
                     + w1r[4*qq+2]*xv.z + w1r[4*qq+3]*xv.w;
            }
            acc += __shfl_xor(acc, 1);
            acc += __shfl_xor(acc, 2);
            if (kc == 0) ((float*)z_l)[js] = fmaxf(acc + b1v, 0.f);
        }
        if (t < TT && w < 3) {
            const float4* hs = m_cur ? ic_l : h_l[p];
            float acc = 0.f;
            #pragma unroll
            for (int kk = 0; kk < 16; ++kk) {
                float4 hv = hs[kk];
                acc += wB[4*kk+0]*hv.x + wB[4*kk+1]*hv.y
                     + wB[4*kk+2]*hv.z + wB[4*kk+3]*hv.w;
            }
            gh_l[tid] = acc;
        } else if (w == 3 && t >= 1 && t <= TT) {
            const float4* hs = h_l[p];
            float acc = b2v;
            #pragma unroll
            for (int kk = 0; kk < 16; ++kk) {
                float4 hv = hs[kk];
                acc += wA[4*kk+0]*hv.x + wA[4*kk+1]*hv.y
                     + wA[4*kk+2]*hv.z + wA[4*kk+3]*hv.w;
            }
            ((float*)y_l[p])[lane] = fmaxf(acc, 0.f);
        }
        __syncthreads();
        if (t < TT && w < 3) {
            float acc = biv;
            #pragma unroll
            for (int kk = 0; kk < 16; ++kk) {
                float4 zv = z_l[kk];
                acc += wA[4*kk+0]*zv.x + wA[4*kk+1]*zv.y
                     + wA[4*kk+2]*zv.z + wA[4*kk+3]*zv.w;
            }
            gi_l[tid] = acc;
        } else if (w == 3 && t >= 2) {
            const float4* yss = y_l[p ^ 1];
            float acc = blv;
            #pragma unroll
            for (int kk = 0; kk < 16; ++kk) {
                float4 yv = yss[kk];
                acc += wB[4*kk+0]*yv.x + wB[4*kk+1]*yv.y
                     + wB[4*kk+2]*yv.z + wB[4*kk+3]*yv.w;
            }
            if (lane < AA)       out[OFF_L + (size_t)((t-2)*BB + b)*AA + lane] = acc;
            else if (lane == AA) out[OFF_V + (size_t)(t-2)*BB + b] = acc;
        }
        __syncthreads();
        if (t < TT && tid < HH) {
            const int j = tid;
            const float irv = gi_l[j], izv = gi_l[HH+j], inn = gi_l[2*HH+j];
            const float hrv = gh_l[j], hzv = gh_l[HH+j], hnv = gh_l[2*HH+j];
            const float heff = m_cur ? ((const float*)ic_l)[j]
                                     : ((const float*)h_l[p])[j];
            const float r  = sigm(irv + hrv);
            const float u  = sigm(izv + hzv);
            const float nn = tanh_(inn + r*(hnv + bhnv));
            ((float*)h_l[p ^ 1])[j] = u*(heff - nn) + nn;
        }
        if (t + 1 < TT && tid < OBS) {
            ((float*)&x_l[p ^ 1][tid>>5])[tid&31] = xnext;
        }
        m_cur = m_next;
        __syncthreads();
    }
    if (tid < HH) out[(size_t)b*HH + tid] = ((const float*)h_l[TT & 1])[tid];
}

extern "C" void kernel_launch(void* const* d_in, const int* in_sizes, int n_in,
                              void* d_out, int out_size, void* d_ws, size_t ws_size,
                              hipStream_t stream) {
    const float* x    = (const float*)d_in[0];
    const void*  mask = (const void*) d_in[1];
    const float* ic   = (const float*)d_in[2];
    const float* W1   = (const float*)d_in[3];
    const float* b1   = (const float*)d_in[4];
    const float* Wi   = (const float*)d_in[5];
    const float* bi   = (const float*)d_in[6];
    const float* Wh   = (const float*)d_in[7];
    const float* bhn  = (const float*)d_in[8];
    const float* W2   = (const float*)d_in[9];
    const float* b2   = (const float*)d_in[10];
    const float* Wl   = (const float*)d_in[11];
    const float* bl   = (const float*)d_in[12];
    const float* Wv   = (const float*)d_in[13];
    const float* bv   = (const float*)d_in[14];
    float* out = (float*)d_out;

    if (ws_size >= WS_NEED) {
        float* gi = (float*)d_ws;
        float* ys = gi + GI_ELEMS;
        // flag lives in out[last value elem]; heads overwrites it last
        uint32_t* flag = (uint32_t*)(out + OFF_V + RT - 1);
        hipMemsetAsync(flag, 0, sizeof(uint32_t), stream);
        detect_mask<<<64, 256, 0, stream>>>((const uint32_t*)mask, flag);
        stem_gi<<<P1_BLOCKS, 256, 0, stream>>>(x, W1, b1, Wi, bi, gi);
        recur9<<<32, 256, 0, stream>>>(gi, mask, flag, ic, Wh, bhn, ys, out);
        heads<<<P3_BLOCKS, 256, 0, stream>>>(ys, W2, b2, Wl, bl, Wv, bv, out);
    } else {
        uint32_t* flag = (uint32_t*)d_ws;
        hipMemsetAsync(flag, 0, sizeof(uint32_t), stream);
        detect_mask<<<64, 256, 0, stream>>>((const uint32_t*)mask, flag);
        gru_agent<<<BB, 256, 0, stream>>>(x, mask, flag, ic, W1, b1, Wi, bi, Wh, bhn,
                                          W2, b2, Wl, bl, Wv, bv, out);
    }
}